// Round 4
// baseline (566.031 us; speedup 1.0000x reference)
//
#include <hip/hip_runtime.h>
#include <stdint.h>

// FeatsInitLayer fused kernel for MI355X (gfx950) — round 3
// (round-2 plan; fixed: nontemporal builtins need clang ext_vector types,
//  not HIP_vector_type wrappers like int4/float4/ushort4)
//
// Reference:
//   x    = emb_W[coords]                                  [N,64]
//   rbf0 = swish(rbf @ W_rbf0 + b_rbf0)                   [E,64]
//   e1   = swish([x_i | x_j | rbf0] @ W_lin + b_lin)      [E,64]
//   e2   = (rbf @ W_rbf1) * e1                            [E,64]
//
// Algebra: cat@W_lin = x_i@W1 + x_j@W2 + rbf0@W3  (W_lin = [W1;W2;W3])
//   emb1[c] = emb_W[c]@W1, emb2[c] = emb_W[c]@W2 + b_lin  (95x64 bf16 tables in LDS)
// Changes vs round-1:
//   * edge gather moved to its own kernel, packed u8|u8 into cid[E] (u16):
//     main loop has NO dependent random loads and NO shuffles.
//   * software pipeline: next tile's rbf + cid loads issued before current
//     tile's compute.
//   * nontemporal loads (rbf, indices) and stores (e1,e2).
//   * t1 = rbf@W_rbf1 MFMA deferred into the epilogue t-loop.

#define N_NODES 100000
#define N_EDGES 800000
#define H_NF 64
#define VOCAB 95
#define NTILES (N_EDGES / 16)   // 50000

typedef __attribute__((ext_vector_type(8))) short short8;
typedef __attribute__((ext_vector_type(4))) float f32x4;
typedef __attribute__((ext_vector_type(4))) int i32x4;
typedef __attribute__((ext_vector_type(4))) unsigned short u16x4;

// ---- ws layout in u16 units ----
#define TAB_STRIDE 66                   // 66 u16 per row: bank-rotates gathers
#define TAB2_OFF   (VOCAB * TAB_STRIDE) // 6270
#define TAB_U16_PAD 12544               // pad to 16B multiple
#define B0_OFF     TAB_U16_PAD          // 8 tiles * 64 lanes * 8 bf16 = 4096
#define W3_OFF     (TAB_U16_PAD + 4096) // 8 frags * 64 * 8 = 4096
#define CID_OFF    (TAB_U16_PAD + 8192) // u16 offset; cid[E] starts 64B-aligned

__device__ __forceinline__ unsigned short f2bf(float x) {
  uint32_t u = __float_as_uint(x);
  return (unsigned short)((u + 0x7FFFu + ((u >> 16) & 1u)) >> 16);  // RNE
}
__device__ __forceinline__ float bf2f(unsigned short b) {
  return __uint_as_float(((uint32_t)b) << 16);
}
__device__ __forceinline__ float swish_f(float x) {
  return x * __builtin_amdgcn_rcpf(1.0f + __expf(-x));
}

// ---------------- prep: tables + bf16 weight fragments into ws ----------------
__global__ void feats_prep(const float* __restrict__ emb_W,
                           const float* __restrict__ W_rbf0,
                           const float* __restrict__ b_rbf0,
                           const float* __restrict__ W_lin,
                           const float* __restrict__ b_lin,
                           const float* __restrict__ W_rbf1,
                           unsigned short* __restrict__ ws16) {
  const int b = blockIdx.x, t = threadIdx.x;  // 64 threads/block
  if (b < VOCAB) {
    const int c = b, h = t;
    float e1 = 0.f, e2 = b_lin[h];
    for (int k = 0; k < 64; ++k) {
      const float w = emb_W[c * 64 + k];
      e1 += w * W_lin[k * 64 + h];            // W1 rows 0..63   (x_i side)
      e2 += w * W_lin[(64 + k) * 64 + h];     // W2 rows 64..127 (x_j side)
    }
    ws16[c * TAB_STRIDE + h] = f2bf(e1);
    ws16[TAB2_OFF + c * TAB_STRIDE + h] = f2bf(e2);
  } else if (b == VOCAB) {
    // B0 fragments: B0[k][n], k<16: [W_rbf0 | W_rbf1]; k==16: [b_rbf0 | 0]; else 0
    // frag layout: [ntile t][lane l][i]  -> element B0[(l>>4)*8+i][t*16+(l&15)]
    for (int idx = t; idx < 4096; idx += 64) {
      const int tt = idx >> 9, l = (idx >> 3) & 63, i = idx & 7;
      const int k = (l >> 4) * 8 + i, n = tt * 16 + (l & 15);
      float v = 0.f;
      if (k < 16)       v = (n < 64) ? W_rbf0[k * 64 + n] : W_rbf1[k * 64 + (n - 64)];
      else if (k == 16) v = (n < 64) ? b_rbf0[n] : 0.f;   // bias row (A has 1.0 at k=16)
      ws16[B0_OFF + idx] = f2bf(v);
    }
  } else {
    // W3 fragments: W3[k][n] = W_lin[128+k][n], frag f = s*4+t
    // element W3[s*32+(l>>4)*8+i][t*16+(l&15)]
    for (int idx = t; idx < 4096; idx += 64) {
      const int f = idx >> 9, l = (idx >> 3) & 63, i = idx & 7;
      const int s = f >> 2, tt = f & 3;
      const int k = s * 32 + (l >> 4) * 8 + i, n = tt * 16 + (l & 15);
      ws16[W3_OFF + idx] = f2bf(W_lin[(128 + k) * 64 + n]);
    }
  }
}

// ---------------- edge gather: cid[e] = coords[node_is[e]] | coords[node_js[e]]<<8 ----
__global__ __launch_bounds__(256) void feats_gather(
    const int* __restrict__ coords, const int* __restrict__ node_is,
    const int* __restrict__ node_js, unsigned short* __restrict__ cid) {
  const int idx = blockIdx.x * 256 + threadIdx.x;   // one thread = 4 edges
  if (idx >= N_EDGES / 4) return;
  const i32x4 vi = __builtin_nontemporal_load((const i32x4*)node_is + idx);
  const i32x4 vj = __builtin_nontemporal_load((const i32x4*)node_js + idx);
  u16x4 r;
  r.x = (unsigned short)(coords[vi.x] | (coords[vj.x] << 8));
  r.y = (unsigned short)(coords[vi.y] | (coords[vj.y] << 8));
  r.z = (unsigned short)(coords[vi.z] | (coords[vj.z] << 8));
  r.w = (unsigned short)(coords[vi.w] | (coords[vj.w] << 8));
  __builtin_nontemporal_store(r, (u16x4*)cid + idx);
}

// ---------------- main fused kernel ----------------
__global__ __launch_bounds__(256) void feats_main(
    const float* __restrict__ rbf, const unsigned short* __restrict__ ws16,
    float* __restrict__ out) {
  __shared__ __align__(16) unsigned short tab[TAB_U16_PAD];   // 25088 B (emb1|emb2, bf16)
  __shared__ __align__(16) unsigned short stage[4][16 * 72];  // 9216 B, per-wave rbf0 transpose

  const int tid = threadIdx.x;
  const int lane = tid & 63;
  const int wv = tid >> 6;
  const int g = lane >> 4;     // 16-lane group 0..3
  const int lm = lane & 15;
  const unsigned short* cid = ws16 + CID_OFF;

  {  // tables -> LDS (16B copies)
    const uint4* src = (const uint4*)ws16;
    uint4* dst = (uint4*)tab;
    for (int i = tid; i < TAB_U16_PAD / 8; i += 256) dst[i] = src[i];
  }

  // B fragments held in registers for the whole kernel
  short8 b0f[8], w3f[2][4];
  {
    const short8* p = (const short8*)(ws16 + B0_OFF);
#pragma unroll
    for (int t = 0; t < 8; ++t) b0f[t] = p[t * 64 + lane];
    const short8* q = (const short8*)(ws16 + W3_OFF);
#pragma unroll
    for (int f = 0; f < 8; ++f) w3f[f >> 2][f & 3] = q[f * 64 + lane];
  }
  __syncthreads();

  float* out_e1 = out;
  float* out_e2 = out + (size_t)N_EDGES * H_NF;
  const f32x4 zf = {0.f, 0.f, 0.f, 0.f};
  unsigned short* st = &stage[wv][0];
  const int stride = gridDim.x * 4;

  // ---- software pipeline: load tile state ----
  int tile = blockIdx.x * 4 + wv;

  auto load_af = [&](int tl) -> short8 {
    short8 a;
    if (lane < 32) {
      const f32x4* rp = (const f32x4*)(rbf + (size_t)(tl * 16 + lm) * 16 + g * 8);
      const f32x4 v0 = __builtin_nontemporal_load(rp);
      const f32x4 v1 = __builtin_nontemporal_load(rp + 1);
      a[0] = f2bf(v0.x); a[1] = f2bf(v0.y); a[2] = f2bf(v0.z); a[3] = f2bf(v0.w);
      a[4] = f2bf(v1.x); a[5] = f2bf(v1.y); a[6] = f2bf(v1.z); a[7] = f2bf(v1.w);
    } else {
      a = (short8){0, 0, 0, 0, 0, 0, 0, 0};
      if (lane < 48) a[0] = (short)0x3F80;  // g==2 -> k=16 -> 1.0f (bias row)
    }
    return a;
  };
  auto load_cid = [&](int tl) -> u16x4 {
    return *(const u16x4*)(cid + tl * 16 + g * 4);   // 8B broadcast per group
  };

  short8 af = (tile < NTILES) ? load_af(tile) : short8{0,0,0,0,0,0,0,0};
  u16x4 cv = (tile < NTILES) ? load_cid(tile) : u16x4{0,0,0,0};

  for (; tile < NTILES; tile += stride) {
    const int ntile = tile + stride;
    // ---- prefetch next tile (loads issue now, consumed next iteration) ----
    short8 af_n = af; u16x4 cv_n = cv;
    if (ntile < NTILES) { af_n = load_af(ntile); cv_n = load_cid(ntile); }

    const int ebase = tile << 4;

    // GEMM1a: t0 = rbf_pad @ [W_rbf0 + bias]   (16 x 64)
    f32x4 t0v[4];
#pragma unroll
    for (int t = 0; t < 4; ++t)
      t0v[t] = __builtin_amdgcn_mfma_f32_16x16x32_bf16(af, b0f[t], zf, 0, 0, 0);

    // swish -> per-wave LDS transpose (C layout: row=g*4+q, col=t*16+lm)
#pragma unroll
    for (int t = 0; t < 4; ++t)
#pragma unroll
      for (int q = 0; q < 4; ++q)
        st[(g * 4 + q) * 72 + t * 16 + lm] = f2bf(swish_f(t0v[t][q]));

    // rbf0 A-fragments: row=lm, k = s*32 + g*8 + i  (144B row stride, aligned b128)
    const short8 a2_0 = *(const short8*)&st[lm * 72 + g * 8];
    const short8 a2_1 = *(const short8*)&st[lm * 72 + 32 + g * 8];

    // GEMM2 + deferred GEMM1b (rbf@W_rbf1) + epilogue
#pragma unroll
    for (int t = 0; t < 4; ++t) {
      f32x4 acc = __builtin_amdgcn_mfma_f32_16x16x32_bf16(a2_0, w3f[0][t], zf, 0, 0, 0);
      acc = __builtin_amdgcn_mfma_f32_16x16x32_bf16(a2_1, w3f[1][t], acc, 0, 0, 0);
      const f32x4 t1 = __builtin_amdgcn_mfma_f32_16x16x32_bf16(af, b0f[4 + t], zf, 0, 0, 0);
      const int hp = t * 16 + lm;
#pragma unroll
      for (int q = 0; q < 4; ++q) {
        const int ci = cv[q] & 0xFF, cj = cv[q] >> 8;
        const float x = acc[q]
                      + bf2f(tab[ci * TAB_STRIDE + hp])
                      + bf2f(tab[TAB2_OFF + cj * TAB_STRIDE + hp]);
        const float e1 = swish_f(x);
        const float e2 = t1[q] * e1;
        const size_t o = (size_t)(ebase + g * 4 + q) * 64 + hp;
        __builtin_nontemporal_store(e1, &out_e1[o]);
        __builtin_nontemporal_store(e2, &out_e2[o]);
      }
    }

    af = af_n; cv = cv_n;
  }
}

extern "C" void kernel_launch(void* const* d_in, const int* in_sizes, int n_in,
                              void* d_out, int out_size, void* d_ws, size_t ws_size,
                              hipStream_t stream) {
  const int* coords    = (const int*)d_in[0];
  const float* rbf     = (const float*)d_in[1];
  const int* node_is   = (const int*)d_in[2];
  const int* node_js   = (const int*)d_in[3];
  const float* emb_W   = (const float*)d_in[4];
  const float* W_rbf0  = (const float*)d_in[5];
  const float* b_rbf0  = (const float*)d_in[6];
  const float* W_lin   = (const float*)d_in[7];
  const float* b_lin   = (const float*)d_in[8];
  const float* W_rbf1  = (const float*)d_in[9];
  unsigned short* ws16 = (unsigned short*)d_ws;
  float* out           = (float*)d_out;

  hipLaunchKernelGGL(feats_prep, dim3(VOCAB + 2), dim3(64), 0, stream,
                     emb_W, W_rbf0, b_rbf0, W_lin, b_lin, W_rbf1, ws16);
  hipLaunchKernelGGL(feats_gather, dim3((N_EDGES / 4 + 255) / 256), dim3(256), 0, stream,
                     coords, node_is, node_js, ws16 + CID_OFF);
  hipLaunchKernelGGL(feats_main, dim3(1024), dim3(256), 0, stream,
                     rbf, ws16, out);
}